// Round 8
// baseline (329.865 us; speedup 1.0000x reference)
//
#include <hip/hip_runtime.h>
#include <hip/hip_fp16.h>

#define H_ 1024
#define W_ 1024
#define RAD 30
#define EPSF 1.3f
#define SH 32            // output rows per block (even; 2-row batches)
#define NSEG (H_ / SH)   // 32 y-segments
#define NT 512           // 8 waves; 2 px/thread over the full 1024-px row
#define NXCD 8

// padded LDS index: breaks stride bank patterns on prefix reads
__device__ __forceinline__ int padidx(int i) { return i + (i >> 3); }
#define PSZ (W_ + (W_ >> 3) + 1)   // padidx(1024)=1152 -> 1153

__device__ __forceinline__ float wscan(float v, int lane) {
#pragma unroll
    for (int d = 1; d < 64; d <<= 1) {
        const float t = __shfl_up(v, d, 64);
        if (lane >= d) v += t;
    }
    return v;
}

// ---------------------------------------------------------------------------
// gf_ab: block = (plane, 32-row segment), 512 threads, full-width row.
// Vertical sliding sums of {R,I,RI,RR} in registers; 2 rows per barrier
// round (2 barriers only; wt ping-ponged); slide rows PREFETCHED one batch
// ahead so HBM latency hides under scan+barrier+LDS work.
// ---------------------------------------------------------------------------
__global__ __launch_bounds__(NT, 6)
void gf_ab(const float* __restrict__ I, const float* __restrict__ R,
           long long in_off, int nb, __half2* __restrict__ AB)
{
    __shared__ float P[8][PSZ];    // [row*4+field]
    __shared__ float wt[2][8][8];  // ping-pong by batch parity

    // bijective XCD swizzle (nb % 8 == 0): consecutive segs -> same XCD
    const int q = nb / NXCD;
    const int bid = (int)blockIdx.x;
    const int sbid = (bid % NXCD) * q + bid / NXCD;
    const int seg = sbid % NSEG;
    const int pl  = sbid / NSEG;

    const int tid = threadIdx.x;
    const int lane = tid & 63, wid = tid >> 6;
    const int x0 = tid * 2;
    const int y0 = seg * SH;
    const long long pb = (long long)pl * (long long)(H_ * W_);
    const long long ib = in_off + pb;

    float icx[2];
#pragma unroll
    for (int j = 0; j < 2; ++j) {
        const int x = x0 + j;
        icx[j] = 1.0f / (float)(min(x + RAD, W_ - 1) - max(x - RAD, 0) + 1);
    }

    if (tid == 0) {
#pragma unroll
        for (int f = 0; f < 8; ++f) P[f][0] = 0.0f;   // padidx(0)==0, once
    }

    float s[4][2];
#pragma unroll
    for (int f = 0; f < 4; ++f) { s[f][0] = 0.0f; s[f][1] = 0.0f; }

    // warm-up rows [y0-RAD, y0+RAD] clipped
    {
        const int wlo = max(0, y0 - RAD), whi = min(H_ - 1, y0 + RAD);
#pragma unroll 4
        for (int yy = wlo; yy <= whi; ++yy) {
            const float2 r2 = *(const float2*)(R + ib + (long long)yy * W_ + x0);
            const float2 i2 = *(const float2*)(I + ib + (long long)yy * W_ + x0);
            s[0][0] += r2.x; s[0][1] += r2.y;
            s[1][0] += i2.x; s[1][1] += i2.y;
            s[2][0] += r2.x * i2.x; s[2][1] += r2.y * i2.y;
            s[3][0] += r2.x * r2.x; s[3][1] += r2.y * r2.y;
        }
    }

    const float2 z2 = make_float2(0.0f, 0.0f);
    // prefetch regs for slide rows: add rows y+31,y+32; sub rows y-30,y-29
    float2 ra0, ia0, ra1, ia1, rb0, ib0v, rb1, ib1v;
#define PF_AB(yy)                                                              \
    {                                                                          \
        const int A0 = (yy) + RAD + 1, A1 = (yy) + RAD + 2;                    \
        const int B0 = (yy) - RAD,     B1 = (yy) - RAD + 1;                    \
        ra0 = (A0 < H_) ? *(const float2*)(R + ib + (long long)A0 * W_ + x0) : z2; \
        ia0 = (A0 < H_) ? *(const float2*)(I + ib + (long long)A0 * W_ + x0) : z2; \
        ra1 = (A1 < H_) ? *(const float2*)(R + ib + (long long)A1 * W_ + x0) : z2; \
        ia1 = (A1 < H_) ? *(const float2*)(I + ib + (long long)A1 * W_ + x0) : z2; \
        rb0 = (B0 >= 0) ? *(const float2*)(R + ib + (long long)B0 * W_ + x0) : z2; \
        ib0v = (B0 >= 0) ? *(const float2*)(I + ib + (long long)B0 * W_ + x0) : z2; \
        rb1 = (B1 >= 0) ? *(const float2*)(R + ib + (long long)B1 * W_ + x0) : z2; \
        ib1v = (B1 >= 0) ? *(const float2*)(I + ib + (long long)B1 * W_ + x0) : z2; \
    }

    PF_AB(y0);   // prologue prefetch for first batch

    for (int y = y0; y < y0 + SH; y += 2) {
        const int p = ((y - y0) >> 1) & 1;
        float ps[8][2], tot[8], wsc[8];

        // ---- consume prefetched slides; snapshot both rows (branchless) ----
#pragma unroll
        for (int f = 0; f < 4; ++f) {
            ps[0 * 4 + f][0] = s[f][0];
            ps[0 * 4 + f][1] = s[f][0] + s[f][1];
        }
        s[0][0] += ra0.x - rb0.x;           s[0][1] += ra0.y - rb0.y;
        s[1][0] += ia0.x - ib0v.x;          s[1][1] += ia0.y - ib0v.y;
        s[2][0] += ra0.x * ia0.x - rb0.x * ib0v.x;
        s[2][1] += ra0.y * ia0.y - rb0.y * ib0v.y;
        s[3][0] += ra0.x * ra0.x - rb0.x * rb0.x;
        s[3][1] += ra0.y * ra0.y - rb0.y * rb0.y;
#pragma unroll
        for (int f = 0; f < 4; ++f) {
            ps[1 * 4 + f][0] = s[f][0];
            ps[1 * 4 + f][1] = s[f][0] + s[f][1];
        }
        s[0][0] += ra1.x - rb1.x;           s[0][1] += ra1.y - rb1.y;
        s[1][0] += ia1.x - ib1v.x;          s[1][1] += ia1.y - ib1v.y;
        s[2][0] += ra1.x * ia1.x - rb1.x * ib1v.x;
        s[2][1] += ra1.y * ia1.y - rb1.y * ib1v.y;
        s[3][0] += ra1.x * ra1.x - rb1.x * rb1.x;
        s[3][1] += ra1.y * ra1.y - rb1.y * rb1.y;

        // ---- issue next batch's prefetch (latency hides under scan+LDS) ----
        if (y + 2 < y0 + SH) PF_AB(y + 2);

        // ---- 8 independent wave scans ----
#pragma unroll
        for (int f = 0; f < 8; ++f) {
            tot[f] = ps[f][1];
            wsc[f] = wscan(tot[f], lane);
            if (lane == 63) wt[p][f][wid] = wsc[f];
        }
        __syncthreads();   // b1: wt visible (also fences prev batch's P reads)

#pragma unroll
        for (int f = 0; f < 8; ++f) {
            float woff = 0.0f;
#pragma unroll
            for (int w = 0; w < 8; ++w)
                if (w < wid) woff += wt[p][f][w];
            const float ex = woff + wsc[f] - tot[f];  // exclusive prefix at x0
            P[f][padidx(x0 + 1)] = ex + ps[f][0];
            P[f][padidx(x0 + 2)] = ex + ps[f][1];
        }
        __syncthreads();   // b2: P visible

#pragma unroll
        for (int r = 0; r < 2; ++r) {
            const int yr = y + r;
            const float icy = 1.0f / (float)(min(yr + RAD, H_ - 1) - max(yr - RAD, 0) + 1);
            __half2 hv[2];
#pragma unroll
            for (int j = 0; j < 2; ++j) {
                const int x = x0 + j;
                const int hi = padidx(min(x + RAD + 1, W_));
                const int lo = padidx(max(x - RAD, 0));
                const float SR = P[r * 4 + 0][hi] - P[r * 4 + 0][lo];
                const float SI = P[r * 4 + 1][hi] - P[r * 4 + 1][lo];
                const float SP = P[r * 4 + 2][hi] - P[r * 4 + 2][lo];
                const float SQ = P[r * 4 + 3][hi] - P[r * 4 + 3][lo];
                const float invN = icx[j] * icy;
                const float mR = SR * invN, mI = SI * invN;
                const float a = (SP * invN - mR * mI) / (SQ * invN - mR * mR + EPSF);
                const float b = mI - a * mR;
                hv[j] = __floats2half2_rn(a, b);
            }
            const long long ob = pb + (long long)yr * W_ + x0;
            uint2 u;
            u.x = *(const unsigned*)&hv[0];
            u.y = *(const unsigned*)&hv[1];
            *(uint2*)(AB + ob) = u;
        }
        // no b3: next batch's b1 already separates P reads from P writes;
        // wt is ping-ponged.
    }
#undef PF_AB
}

// ---------------------------------------------------------------------------
// gf_cd: same structure over packed half2 {a,b}; out = mean_a * R + mean_b.
// ---------------------------------------------------------------------------
__global__ __launch_bounds__(NT, 6)
void gf_cd(const __half2* __restrict__ AB, const float* __restrict__ Rimg,
           long long in_off, int nb, float* __restrict__ out)
{
    __shared__ float P[4][PSZ];    // [row*2+field]
    __shared__ float wt[2][4][8];

    const int q = nb / NXCD;
    const int bid = (int)blockIdx.x;
    const int sbid = (bid % NXCD) * q + bid / NXCD;
    const int seg = sbid % NSEG;
    const int pl  = sbid / NSEG;

    const int tid = threadIdx.x;
    const int lane = tid & 63, wid = tid >> 6;
    const int x0 = tid * 2;
    const int y0 = seg * SH;
    const long long pb = (long long)pl * (long long)(H_ * W_);
    const long long ib = in_off + pb;

    float icx[2];
#pragma unroll
    for (int j = 0; j < 2; ++j) {
        const int x = x0 + j;
        icx[j] = 1.0f / (float)(min(x + RAD, W_ - 1) - max(x - RAD, 0) + 1);
    }

    if (tid == 0) {
#pragma unroll
        for (int f = 0; f < 4; ++f) P[f][0] = 0.0f;
    }

    float s[2][2];
    s[0][0] = s[0][1] = s[1][0] = s[1][1] = 0.0f;

    {
        const int wlo = max(0, y0 - RAD), whi = min(H_ - 1, y0 + RAD);
#pragma unroll 4
        for (int yy = wlo; yy <= whi; ++yy) {
            const uint2 u = *(const uint2*)(AB + pb + (long long)yy * W_ + x0);
            const float2 ab0 = __half22float2(*(const __half2*)&u.x);
            const float2 ab1 = __half22float2(*(const __half2*)&u.y);
            s[0][0] += ab0.x; s[1][0] += ab0.y;
            s[0][1] += ab1.x; s[1][1] += ab1.y;
        }
    }

    const uint2 zu = make_uint2(0u, 0u);   // half2 zeros
    uint2 ua0, ua1, ub0, ub1;
    float2 pr0, pr1;                       // R rows y, y+1 for epilogue
#define PF_CD(yy)                                                              \
    {                                                                          \
        const int A0 = (yy) + RAD + 1, A1 = (yy) + RAD + 2;                    \
        const int B0 = (yy) - RAD,     B1 = (yy) - RAD + 1;                    \
        ua0 = (A0 < H_) ? *(const uint2*)(AB + pb + (long long)A0 * W_ + x0) : zu; \
        ua1 = (A1 < H_) ? *(const uint2*)(AB + pb + (long long)A1 * W_ + x0) : zu; \
        ub0 = (B0 >= 0) ? *(const uint2*)(AB + pb + (long long)B0 * W_ + x0) : zu; \
        ub1 = (B1 >= 0) ? *(const uint2*)(AB + pb + (long long)B1 * W_ + x0) : zu; \
        pr0 = *(const float2*)(Rimg + ib + (long long)(yy) * W_ + x0);         \
        pr1 = *(const float2*)(Rimg + ib + (long long)((yy) + 1) * W_ + x0);   \
    }

    PF_CD(y0);

    for (int y = y0; y < y0 + SH; y += 2) {
        const int p = ((y - y0) >> 1) & 1;
        float ps[4][2], tot[4], wsc[4];
        const float2 r0 = pr0, r1 = pr1;

#pragma unroll
        for (int f = 0; f < 2; ++f) {
            ps[0 * 2 + f][0] = s[f][0];
            ps[0 * 2 + f][1] = s[f][0] + s[f][1];
        }
        {
            const float2 a0 = __half22float2(*(const __half2*)&ua0.x);
            const float2 a1 = __half22float2(*(const __half2*)&ua0.y);
            const float2 b0 = __half22float2(*(const __half2*)&ub0.x);
            const float2 b1 = __half22float2(*(const __half2*)&ub0.y);
            s[0][0] += a0.x - b0.x; s[1][0] += a0.y - b0.y;
            s[0][1] += a1.x - b1.x; s[1][1] += a1.y - b1.y;
        }
#pragma unroll
        for (int f = 0; f < 2; ++f) {
            ps[1 * 2 + f][0] = s[f][0];
            ps[1 * 2 + f][1] = s[f][0] + s[f][1];
        }
        {
            const float2 a0 = __half22float2(*(const __half2*)&ua1.x);
            const float2 a1 = __half22float2(*(const __half2*)&ua1.y);
            const float2 b0 = __half22float2(*(const __half2*)&ub1.x);
            const float2 b1 = __half22float2(*(const __half2*)&ub1.y);
            s[0][0] += a0.x - b0.x; s[1][0] += a0.y - b0.y;
            s[0][1] += a1.x - b1.x; s[1][1] += a1.y - b1.y;
        }

        if (y + 2 < y0 + SH) PF_CD(y + 2);

#pragma unroll
        for (int f = 0; f < 4; ++f) {
            tot[f] = ps[f][1];
            wsc[f] = wscan(tot[f], lane);
            if (lane == 63) wt[p][f][wid] = wsc[f];
        }
        __syncthreads();   // b1

#pragma unroll
        for (int f = 0; f < 4; ++f) {
            float woff = 0.0f;
#pragma unroll
            for (int w = 0; w < 8; ++w)
                if (w < wid) woff += wt[p][f][w];
            const float ex = woff + wsc[f] - tot[f];
            P[f][padidx(x0 + 1)] = ex + ps[f][0];
            P[f][padidx(x0 + 2)] = ex + ps[f][1];
        }
        __syncthreads();   // b2

#pragma unroll
        for (int r = 0; r < 2; ++r) {
            const int yr = y + r;
            const float icy = 1.0f / (float)(min(yr + RAD, H_ - 1) - max(yr - RAD, 0) + 1);
            const long long og = ib + (long long)yr * W_ + x0;
            const float2 rr = (r == 0) ? r0 : r1;
            float ov[2];
            const float rv[2] = {rr.x, rr.y};
#pragma unroll
            for (int j = 0; j < 2; ++j) {
                const int x = x0 + j;
                const int hi = padidx(min(x + RAD + 1, W_));
                const int lo = padidx(max(x - RAD, 0));
                const float SA = P[r * 2 + 0][hi] - P[r * 2 + 0][lo];
                const float SB = P[r * 2 + 1][hi] - P[r * 2 + 1][lo];
                const float invN = icx[j] * icy;
                ov[j] = (SA * invN) * rv[j] + SB * invN;
            }
            *(float2*)(out + og) = make_float2(ov[0], ov[1]);
        }
        // no b3 (see gf_ab)
    }
#undef PF_CD
}

// ---------------------------------------------------------------------------
extern "C" void kernel_launch(void* const* d_in, const int* in_sizes, int n_in,
                              void* d_out, int out_size, void* d_ws, size_t ws_size,
                              hipStream_t stream)
{
    const float* I = (const float*)d_in[0];   // image to filter
    const float* R = (const float*)d_in[1];   // guidance image
    float* out = (float*)d_out;

    const long long plane = (long long)H_ * W_;
    const int P_ = (int)(in_sizes[0] / plane);              // 24 planes
    const size_t ab_pb = (size_t)plane * sizeof(__half2);   // 4 MB/plane

    int CH = (int)(ws_size / ab_pb);
    if (CH > P_) CH = P_;
    if (CH < 1) CH = 1;

    __half2* AB = (__half2*)d_ws;

    for (int p0 = 0; p0 < P_; p0 += CH) {
        const int pc = (P_ - p0 < CH) ? (P_ - p0) : CH;
        const long long in_off = (long long)p0 * plane;
        const int nb = NSEG * pc;   // 32*pc

        hipLaunchKernelGGL(gf_ab, dim3(nb), dim3(NT), 0, stream,
                           I, R, in_off, nb, AB);
        hipLaunchKernelGGL(gf_cd, dim3(nb), dim3(NT), 0, stream,
                           AB, R, in_off, nb, out);
    }
}

// Round 9
// 233.532 us; speedup vs baseline: 1.4125x; 1.4125x over previous
//
#include <hip/hip_runtime.h>
#include <hip/hip_fp16.h>

#define H_ 1024
#define W_ 1024
#define RAD 30
#define EPSF 1.3f
#define SH 32            // output rows per block (even; 2-row batches)
#define NSEG (H_ / SH)   // 32 y-segments
#define NT 512           // 8 waves; 2 px/thread over the full 1024-px row
#define NXCD 8

// padded LDS index: breaks stride bank patterns on prefix reads
__device__ __forceinline__ int padidx(int i) { return i + (i >> 3); }
#define PSZ (W_ + (W_ >> 3) + 1)   // padidx(1024)=1152 -> 1153

// ---- DPP wave64 inclusive scan: 6 VALU adds, no LDS traffic ----
// row_shr:1,2,4,8 within 16-lane rows; row_bcast:15 -> rows 1,3;
// row_bcast:31 -> rows 2,3.  bound_ctrl=1 => invalid source reads 0.
#define DPP_ADD(v, ctrl, rmask, bc)                                            \
    ((v) + __int_as_float(__builtin_amdgcn_update_dpp(                         \
               0, __float_as_int(v), (ctrl), (rmask), 0xf, (bc))))

__device__ __forceinline__ float wscan_dpp(float v) {
    v = DPP_ADD(v, 0x111, 0xf, true);   // row_shr:1
    v = DPP_ADD(v, 0x112, 0xf, true);   // row_shr:2
    v = DPP_ADD(v, 0x114, 0xf, true);   // row_shr:4
    v = DPP_ADD(v, 0x118, 0xf, true);   // row_shr:8
    v = DPP_ADD(v, 0x142, 0xa, false);  // row_bcast:15 to rows 1,3
    v = DPP_ADD(v, 0x143, 0xc, false);  // row_bcast:31 to rows 2,3
    return v;
}

// ---- non-temporal 8B helpers (keep L3 for reused data) ----
__device__ __forceinline__ void nt_store_u64(void* p, unsigned long long v) {
    __builtin_nontemporal_store(v, (unsigned long long*)p);
}
__device__ __forceinline__ unsigned long long nt_load_u64(const void* p) {
    return __builtin_nontemporal_load((const unsigned long long*)p);
}

// ---------------------------------------------------------------------------
// gf_ab: block = (plane, 32-row segment), 512 threads, full-width row.
// Vertical sliding sums of {R,I,RI,RR} in registers; 2 rows per barrier
// round (2 barriers); DPP wave scans; AB written non-temporally so I/R
// stay L3-resident for halo re-reads.
// ---------------------------------------------------------------------------
__global__ __launch_bounds__(NT, 6)
void gf_ab(const float* __restrict__ I, const float* __restrict__ R,
           long long in_off, int nb, __half2* __restrict__ AB)
{
    __shared__ float P[8][PSZ];    // [row*4+field]
    __shared__ float wt[8][8];

    // bijective XCD swizzle (nb % 8 == 0): consecutive segs -> same XCD
    const int q = nb / NXCD;
    const int bid = (int)blockIdx.x;
    const int sbid = (bid % NXCD) * q + bid / NXCD;
    const int seg = sbid % NSEG;
    const int pl  = sbid / NSEG;

    const int tid = threadIdx.x;
    const int wid = tid >> 6;
    const int x0 = tid * 2;
    const int y0 = seg * SH;
    const long long pb = (long long)pl * (long long)(H_ * W_);
    const long long ib = in_off + pb;

    float icx[2];
#pragma unroll
    for (int j = 0; j < 2; ++j) {
        const int x = x0 + j;
        icx[j] = 1.0f / (float)(min(x + RAD, W_ - 1) - max(x - RAD, 0) + 1);
    }

    if (tid == 0) {
#pragma unroll
        for (int f = 0; f < 8; ++f) P[f][0] = 0.0f;   // padidx(0)==0, once
    }

    float s[4][2];
#pragma unroll
    for (int f = 0; f < 4; ++f) { s[f][0] = 0.0f; s[f][1] = 0.0f; }

    // warm-up rows [y0-RAD, y0+RAD] clipped
    {
        const int wlo = max(0, y0 - RAD), whi = min(H_ - 1, y0 + RAD);
#pragma unroll 4
        for (int yy = wlo; yy <= whi; ++yy) {
            const float2 r2 = *(const float2*)(R + ib + (long long)yy * W_ + x0);
            const float2 i2 = *(const float2*)(I + ib + (long long)yy * W_ + x0);
            s[0][0] += r2.x; s[0][1] += r2.y;
            s[1][0] += i2.x; s[1][1] += i2.y;
            s[2][0] += r2.x * i2.x; s[2][1] += r2.y * i2.y;
            s[3][0] += r2.x * r2.x; s[3][1] += r2.y * r2.y;
        }
    }

    for (int y = y0; y < y0 + SH; y += 2) {
        float ps[8][2], tot[8], wsc[8];

        // ---- snapshot row y, slide; snapshot row y+1, slide ----
#pragma unroll
        for (int r = 0; r < 2; ++r) {
            const int yr = y + r;
#pragma unroll
            for (int f = 0; f < 4; ++f) {
                ps[r * 4 + f][0] = s[f][0];
                ps[r * 4 + f][1] = s[f][0] + s[f][1];
            }
            const int ya = yr + RAD + 1, yb = yr - RAD;
            if (ya < H_) {
                const float2 r2 = *(const float2*)(R + ib + (long long)ya * W_ + x0);
                const float2 i2 = *(const float2*)(I + ib + (long long)ya * W_ + x0);
                s[0][0] += r2.x; s[0][1] += r2.y;
                s[1][0] += i2.x; s[1][1] += i2.y;
                s[2][0] += r2.x * i2.x; s[2][1] += r2.y * i2.y;
                s[3][0] += r2.x * r2.x; s[3][1] += r2.y * r2.y;
            }
            if (yb >= 0) {
                const float2 r2 = *(const float2*)(R + ib + (long long)yb * W_ + x0);
                const float2 i2 = *(const float2*)(I + ib + (long long)yb * W_ + x0);
                s[0][0] -= r2.x; s[0][1] -= r2.y;
                s[1][0] -= i2.x; s[1][1] -= i2.y;
                s[2][0] -= r2.x * i2.x; s[2][1] -= r2.y * i2.y;
                s[3][0] -= r2.x * r2.x; s[3][1] -= r2.y * r2.y;
            }
        }

        // ---- 8 independent DPP wave scans ----
#pragma unroll
        for (int f = 0; f < 8; ++f) {
            tot[f] = ps[f][1];
            wsc[f] = wscan_dpp(tot[f]);
            if ((tid & 63) == 63) wt[f][wid] = wsc[f];
        }
        __syncthreads();   // b1: wt visible (also fences prev batch's P reads)

#pragma unroll
        for (int f = 0; f < 8; ++f) {
            float woff = 0.0f;
#pragma unroll
            for (int w = 0; w < 8; ++w)
                if (w < wid) woff += wt[f][w];
            const float ex = woff + wsc[f] - tot[f];  // exclusive prefix at x0
            P[f][padidx(x0 + 1)] = ex + ps[f][0];
            P[f][padidx(x0 + 2)] = ex + ps[f][1];
        }
        __syncthreads();   // b2: P visible

#pragma unroll
        for (int r = 0; r < 2; ++r) {
            const int yr = y + r;
            const float icy = 1.0f / (float)(min(yr + RAD, H_ - 1) - max(yr - RAD, 0) + 1);
            __half2 hv[2];
#pragma unroll
            for (int j = 0; j < 2; ++j) {
                const int x = x0 + j;
                const int hi = padidx(min(x + RAD + 1, W_));
                const int lo = padidx(max(x - RAD, 0));
                const float SR = P[r * 4 + 0][hi] - P[r * 4 + 0][lo];
                const float SI = P[r * 4 + 1][hi] - P[r * 4 + 1][lo];
                const float SP = P[r * 4 + 2][hi] - P[r * 4 + 2][lo];
                const float SQ = P[r * 4 + 3][hi] - P[r * 4 + 3][lo];
                const float invN = icx[j] * icy;
                const float mR = SR * invN, mI = SI * invN;
                const float a = (SP * invN - mR * mI) / (SQ * invN - mR * mR + EPSF);
                const float b = mI - a * mR;
                hv[j] = __floats2half2_rn(a, b);
            }
            unsigned long long u =
                (unsigned long long)(*(const unsigned*)&hv[0]) |
                ((unsigned long long)(*(const unsigned*)&hv[1]) << 32);
            nt_store_u64(AB + pb + (long long)yr * W_ + x0, u);
        }
        // no b3: next batch's b1 orders P reads vs P writes; wt writes for
        // batch k+1 occur only after all waves passed b2 of batch k.
    }
}

// ---------------------------------------------------------------------------
// gf_cd: same structure over packed half2 {a,b}; out = mean_a * R + mean_b.
// AB loads cached (halo reuse); R load + out store non-temporal.
// ---------------------------------------------------------------------------
__global__ __launch_bounds__(NT, 6)
void gf_cd(const __half2* __restrict__ AB, const float* __restrict__ Rimg,
           long long in_off, int nb, float* __restrict__ out)
{
    __shared__ float P[4][PSZ];    // [row*2+field]
    __shared__ float wt[4][8];

    const int q = nb / NXCD;
    const int bid = (int)blockIdx.x;
    const int sbid = (bid % NXCD) * q + bid / NXCD;
    const int seg = sbid % NSEG;
    const int pl  = sbid / NSEG;

    const int tid = threadIdx.x;
    const int wid = tid >> 6;
    const int x0 = tid * 2;
    const int y0 = seg * SH;
    const long long pb = (long long)pl * (long long)(H_ * W_);
    const long long ib = in_off + pb;

    float icx[2];
#pragma unroll
    for (int j = 0; j < 2; ++j) {
        const int x = x0 + j;
        icx[j] = 1.0f / (float)(min(x + RAD, W_ - 1) - max(x - RAD, 0) + 1);
    }

    if (tid == 0) {
#pragma unroll
        for (int f = 0; f < 4; ++f) P[f][0] = 0.0f;
    }

    float s[2][2];
    s[0][0] = s[0][1] = s[1][0] = s[1][1] = 0.0f;

    {
        const int wlo = max(0, y0 - RAD), whi = min(H_ - 1, y0 + RAD);
#pragma unroll 4
        for (int yy = wlo; yy <= whi; ++yy) {
            const uint2 u = *(const uint2*)(AB + pb + (long long)yy * W_ + x0);
            const float2 ab0 = __half22float2(*(const __half2*)&u.x);
            const float2 ab1 = __half22float2(*(const __half2*)&u.y);
            s[0][0] += ab0.x; s[1][0] += ab0.y;
            s[0][1] += ab1.x; s[1][1] += ab1.y;
        }
    }

    for (int y = y0; y < y0 + SH; y += 2) {
        float ps[4][2], tot[4], wsc[4];

#pragma unroll
        for (int r = 0; r < 2; ++r) {
            const int yr = y + r;
#pragma unroll
            for (int f = 0; f < 2; ++f) {
                ps[r * 2 + f][0] = s[f][0];
                ps[r * 2 + f][1] = s[f][0] + s[f][1];
            }
            const int ya = yr + RAD + 1, yb = yr - RAD;
            if (ya < H_) {
                const uint2 u = *(const uint2*)(AB + pb + (long long)ya * W_ + x0);
                const float2 a0 = __half22float2(*(const __half2*)&u.x);
                const float2 a1 = __half22float2(*(const __half2*)&u.y);
                s[0][0] += a0.x; s[1][0] += a0.y;
                s[0][1] += a1.x; s[1][1] += a1.y;
            }
            if (yb >= 0) {
                const uint2 u = *(const uint2*)(AB + pb + (long long)yb * W_ + x0);
                const float2 a0 = __half22float2(*(const __half2*)&u.x);
                const float2 a1 = __half22float2(*(const __half2*)&u.y);
                s[0][0] -= a0.x; s[1][0] -= a0.y;
                s[0][1] -= a1.x; s[1][1] -= a1.y;
            }
        }

#pragma unroll
        for (int f = 0; f < 4; ++f) {
            tot[f] = ps[f][1];
            wsc[f] = wscan_dpp(tot[f]);
            if ((tid & 63) == 63) wt[f][wid] = wsc[f];
        }
        __syncthreads();   // b1

#pragma unroll
        for (int f = 0; f < 4; ++f) {
            float woff = 0.0f;
#pragma unroll
            for (int w = 0; w < 8; ++w)
                if (w < wid) woff += wt[f][w];
            const float ex = woff + wsc[f] - tot[f];
            P[f][padidx(x0 + 1)] = ex + ps[f][0];
            P[f][padidx(x0 + 2)] = ex + ps[f][1];
        }
        __syncthreads();   // b2

#pragma unroll
        for (int r = 0; r < 2; ++r) {
            const int yr = y + r;
            const float icy = 1.0f / (float)(min(yr + RAD, H_ - 1) - max(yr - RAD, 0) + 1);
            const long long og = ib + (long long)yr * W_ + x0;
            const unsigned long long ru = nt_load_u64(Rimg + og);
            float rv[2];
            *(unsigned*)&rv[0] = (unsigned)(ru & 0xffffffffu);
            *(unsigned*)&rv[1] = (unsigned)(ru >> 32);
            float ov[2];
#pragma unroll
            for (int j = 0; j < 2; ++j) {
                const int x = x0 + j;
                const int hi = padidx(min(x + RAD + 1, W_));
                const int lo = padidx(max(x - RAD, 0));
                const float SA = P[r * 2 + 0][hi] - P[r * 2 + 0][lo];
                const float SB = P[r * 2 + 1][hi] - P[r * 2 + 1][lo];
                const float invN = icx[j] * icy;
                ov[j] = (SA * invN) * rv[j] + SB * invN;
            }
            unsigned long long uo =
                (unsigned long long)(*(const unsigned*)&ov[0]) |
                ((unsigned long long)(*(const unsigned*)&ov[1]) << 32);
            nt_store_u64(out + og, uo);
        }
        // no b3 (see gf_ab)
    }
}

// ---------------------------------------------------------------------------
extern "C" void kernel_launch(void* const* d_in, const int* in_sizes, int n_in,
                              void* d_out, int out_size, void* d_ws, size_t ws_size,
                              hipStream_t stream)
{
    const float* I = (const float*)d_in[0];   // image to filter
    const float* R = (const float*)d_in[1];   // guidance image
    float* out = (float*)d_out;

    const long long plane = (long long)H_ * W_;
    const int P_ = (int)(in_sizes[0] / plane);              // 24 planes
    const size_t ab_pb = (size_t)plane * sizeof(__half2);   // 4 MB/plane

    int CH = (int)(ws_size / ab_pb);
    if (CH > P_) CH = P_;
    if (CH < 1) CH = 1;

    __half2* AB = (__half2*)d_ws;

    for (int p0 = 0; p0 < P_; p0 += CH) {
        const int pc = (P_ - p0 < CH) ? (P_ - p0) : CH;
        const long long in_off = (long long)p0 * plane;
        const int nb = NSEG * pc;   // 32*pc

        hipLaunchKernelGGL(gf_ab, dim3(nb), dim3(NT), 0, stream,
                           I, R, in_off, nb, AB);
        hipLaunchKernelGGL(gf_cd, dim3(nb), dim3(NT), 0, stream,
                           AB, R, in_off, nb, out);
    }
}

// Round 10
// 226.443 us; speedup vs baseline: 1.4567x; 1.0313x over previous
//
#include <hip/hip_runtime.h>
#include <hip/hip_fp16.h>

#define H_ 1024
#define W_ 1024
#define RAD 30
#define EPSF 1.3f
#define SH 32            // output rows per block (even; 2-row batches)
#define NSEG (H_ / SH)   // 32 y-segments
#define NT 512           // 8 waves; 2 px/thread over the full 1024-px row
#define NXCD 8

// ---- DPP wave64 inclusive scan: 6 VALU adds, no LDS traffic ----
#define DPP_ADD(v, ctrl, rmask, bc)                                            \
    ((v) + __int_as_float(__builtin_amdgcn_update_dpp(                         \
               0, __float_as_int(v), (ctrl), (rmask), 0xf, (bc))))

__device__ __forceinline__ float wscan_dpp(float v) {
    v = DPP_ADD(v, 0x111, 0xf, true);   // row_shr:1
    v = DPP_ADD(v, 0x112, 0xf, true);   // row_shr:2
    v = DPP_ADD(v, 0x114, 0xf, true);   // row_shr:4
    v = DPP_ADD(v, 0x118, 0xf, true);   // row_shr:8
    v = DPP_ADD(v, 0x142, 0xa, false);  // row_bcast:15 -> rows 1,3
    v = DPP_ADD(v, 0x143, 0xc, false);  // row_bcast:31 -> rows 2,3
    return v;
}

// ---- non-temporal 8B helpers (keep L3 for reused data) ----
__device__ __forceinline__ void nt_store_u64(void* p, unsigned long long v) {
    __builtin_nontemporal_store(v, (unsigned long long*)p);
}
__device__ __forceinline__ unsigned long long nt_load_u64(const void* p) {
    return __builtin_nontemporal_load((const unsigned long long*)p);
}

// ---------------------------------------------------------------------------
// gf_ab: block = (plane, 32-row segment), 512 threads, full-width row.
// Prefix arrays pos-major: P2[pos*5 + k], k=0..3 data float2 slots
// (k=0: row0{R,I}, k=1: row0{RI,RR}, k=2: row1{R,I}, k=3: row1{RI,RR}),
// k=4 pad. All LDS traffic b64/b128.
// ---------------------------------------------------------------------------
__global__ __launch_bounds__(NT, 6)
void gf_ab(const float* __restrict__ I, const float* __restrict__ R,
           long long in_off, int nb, __half2* __restrict__ AB)
{
    __shared__ float2 P2[(W_ + 1) * 5];   // 1025*5*8B = 41 KB
    __shared__ float4 WT[8][2];           // per-wave scan totals (8 channels)

    // bijective XCD swizzle (nb % 8 == 0): consecutive segs -> same XCD
    const int q = nb / NXCD;
    const int bid = (int)blockIdx.x;
    const int sbid = (bid % NXCD) * q + bid / NXCD;
    const int seg = sbid % NSEG;
    const int pl  = sbid / NSEG;

    const int tid = threadIdx.x;
    const int lane = tid & 63;
    const int wid = __builtin_amdgcn_readfirstlane(tid) >> 6;  // wave-uniform SGPR
    const int x0 = tid * 2;
    const int y0 = seg * SH;
    const long long pb = (long long)pl * (long long)(H_ * W_);
    const long long ib = in_off + pb;

    float icx[2];
#pragma unroll
    for (int j = 0; j < 2; ++j) {
        const int x = x0 + j;
        icx[j] = 1.0f / (float)(min(x + RAD, W_ - 1) - max(x - RAD, 0) + 1);
    }

    if (tid == 0) {
#pragma unroll
        for (int k = 0; k < 4; ++k) P2[k] = make_float2(0.0f, 0.0f);  // pos 0
    }

    float s[4][2];
#pragma unroll
    for (int f = 0; f < 4; ++f) { s[f][0] = 0.0f; s[f][1] = 0.0f; }

    // warm-up rows [y0-RAD, y0+RAD] clipped
    {
        const int wlo = max(0, y0 - RAD), whi = min(H_ - 1, y0 + RAD);
#pragma unroll 4
        for (int yy = wlo; yy <= whi; ++yy) {
            const float2 r2 = *(const float2*)(R + ib + (long long)yy * W_ + x0);
            const float2 i2 = *(const float2*)(I + ib + (long long)yy * W_ + x0);
            s[0][0] += r2.x; s[0][1] += r2.y;
            s[1][0] += i2.x; s[1][1] += i2.y;
            s[2][0] += r2.x * i2.x; s[2][1] += r2.y * i2.y;
            s[3][0] += r2.x * r2.x; s[3][1] += r2.y * r2.y;
        }
    }

    for (int y = y0; y < y0 + SH; y += 2) {
        float ps[8][2], tot[8], wsc[8];

        // ---- snapshot row y, slide; snapshot row y+1, slide ----
#pragma unroll
        for (int r = 0; r < 2; ++r) {
            const int yr = y + r;
#pragma unroll
            for (int f = 0; f < 4; ++f) {
                ps[r * 4 + f][0] = s[f][0];
                ps[r * 4 + f][1] = s[f][0] + s[f][1];
            }
            const int ya = yr + RAD + 1, yb = yr - RAD;
            if (ya < H_) {
                const float2 r2 = *(const float2*)(R + ib + (long long)ya * W_ + x0);
                const float2 i2 = *(const float2*)(I + ib + (long long)ya * W_ + x0);
                s[0][0] += r2.x; s[0][1] += r2.y;
                s[1][0] += i2.x; s[1][1] += i2.y;
                s[2][0] += r2.x * i2.x; s[2][1] += r2.y * i2.y;
                s[3][0] += r2.x * r2.x; s[3][1] += r2.y * r2.y;
            }
            if (yb >= 0) {
                const float2 r2 = *(const float2*)(R + ib + (long long)yb * W_ + x0);
                const float2 i2 = *(const float2*)(I + ib + (long long)yb * W_ + x0);
                s[0][0] -= r2.x; s[0][1] -= r2.y;
                s[1][0] -= i2.x; s[1][1] -= i2.y;
                s[2][0] -= r2.x * i2.x; s[2][1] -= r2.y * i2.y;
                s[3][0] -= r2.x * r2.x; s[3][1] -= r2.y * r2.y;
            }
        }

        // ---- 8 independent DPP wave scans ----
#pragma unroll
        for (int ch = 0; ch < 8; ++ch) {
            tot[ch] = ps[ch][1];
            wsc[ch] = wscan_dpp(tot[ch]);
        }
        if (lane == 63) {
            WT[wid][0] = make_float4(wsc[0], wsc[1], wsc[2], wsc[3]);
            WT[wid][1] = make_float4(wsc[4], wsc[5], wsc[6], wsc[7]);
        }
        __syncthreads();   // b1: WT visible (also fences prev batch's P2 reads)

        // wave-uniform combine loop (<=7 iters, 2 x b128 each)
        float woA[4] = {0, 0, 0, 0}, woB[4] = {0, 0, 0, 0};
        for (int w = 0; w < wid; ++w) {
            const float4 a = WT[w][0], b = WT[w][1];
            woA[0] += a.x; woA[1] += a.y; woA[2] += a.z; woA[3] += a.w;
            woB[0] += b.x; woB[1] += b.y; woB[2] += b.z; woB[3] += b.w;
        }

        float pv1[8], pv2[8];
#pragma unroll
        for (int qd = 0; qd < 4; ++qd) {
            const float exA = woA[qd] + wsc[qd] - tot[qd];
            pv1[qd] = exA + ps[qd][0];
            pv2[qd] = exA + ps[qd][1];
            const float exB = woB[qd] + wsc[4 + qd] - tot[4 + qd];
            pv1[4 + qd] = exB + ps[4 + qd][0];
            pv2[4 + qd] = exB + ps[4 + qd][1];
        }
        {
            const int i1 = (x0 + 1) * 5, i2 = (x0 + 2) * 5;
            P2[i1 + 0] = make_float2(pv1[0], pv1[1]);
            P2[i1 + 1] = make_float2(pv1[2], pv1[3]);
            P2[i1 + 2] = make_float2(pv1[4], pv1[5]);
            P2[i1 + 3] = make_float2(pv1[6], pv1[7]);
            P2[i2 + 0] = make_float2(pv2[0], pv2[1]);
            P2[i2 + 1] = make_float2(pv2[2], pv2[3]);
            P2[i2 + 2] = make_float2(pv2[4], pv2[5]);
            P2[i2 + 3] = make_float2(pv2[6], pv2[7]);
        }
        __syncthreads();   // b2: P2 visible

#pragma unroll
        for (int r = 0; r < 2; ++r) {
            const int yr = y + r;
            const float icy = 1.0f / (float)(min(yr + RAD, H_ - 1) - max(yr - RAD, 0) + 1);
            __half2 hv[2];
#pragma unroll
            for (int j = 0; j < 2; ++j) {
                const int x = x0 + j;
                const int hi = min(x + RAD + 1, W_) * 5;
                const int lo = max(x - RAD, 0) * 5;
                const float2 ha = P2[hi + 2 * r + 0];
                const float2 hb = P2[hi + 2 * r + 1];
                const float2 la = P2[lo + 2 * r + 0];
                const float2 lb = P2[lo + 2 * r + 1];
                const float SR = ha.x - la.x;
                const float SI = ha.y - la.y;
                const float SP = hb.x - lb.x;
                const float SQ = hb.y - lb.y;
                const float invN = icx[j] * icy;
                const float mR = SR * invN, mI = SI * invN;
                const float a = (SP * invN - mR * mI) / (SQ * invN - mR * mR + EPSF);
                const float b = mI - a * mR;
                hv[j] = __floats2half2_rn(a, b);
            }
            unsigned long long u =
                (unsigned long long)(*(const unsigned*)&hv[0]) |
                ((unsigned long long)(*(const unsigned*)&hv[1]) << 32);
            nt_store_u64(AB + pb + (long long)yr * W_ + x0, u);
        }
        // no b3: next batch's b1 orders P2/WT reads vs writes (all waves must
        // finish epilogue reads before reaching b1 of the next batch).
    }
}

// ---------------------------------------------------------------------------
// gf_cd: same structure over packed half2 {a,b}; out = mean_a * R + mean_b.
// P2[pos*3 + k]: k=0: row0{a,b}, k=1: row1{a,b}, k=2 pad.
// ---------------------------------------------------------------------------
__global__ __launch_bounds__(NT, 6)
void gf_cd(const __half2* __restrict__ AB, const float* __restrict__ Rimg,
           long long in_off, int nb, float* __restrict__ out)
{
    __shared__ float2 P2[(W_ + 1) * 3];   // 24.6 KB
    __shared__ float4 WT[8][1];

    const int q = nb / NXCD;
    const int bid = (int)blockIdx.x;
    const int sbid = (bid % NXCD) * q + bid / NXCD;
    const int seg = sbid % NSEG;
    const int pl  = sbid / NSEG;

    const int tid = threadIdx.x;
    const int lane = tid & 63;
    const int wid = __builtin_amdgcn_readfirstlane(tid) >> 6;
    const int x0 = tid * 2;
    const int y0 = seg * SH;
    const long long pb = (long long)pl * (long long)(H_ * W_);
    const long long ib = in_off + pb;

    float icx[2];
#pragma unroll
    for (int j = 0; j < 2; ++j) {
        const int x = x0 + j;
        icx[j] = 1.0f / (float)(min(x + RAD, W_ - 1) - max(x - RAD, 0) + 1);
    }

    if (tid == 0) {
        P2[0] = make_float2(0.0f, 0.0f);
        P2[1] = make_float2(0.0f, 0.0f);
    }

    float s[2][2];
    s[0][0] = s[0][1] = s[1][0] = s[1][1] = 0.0f;

    {
        const int wlo = max(0, y0 - RAD), whi = min(H_ - 1, y0 + RAD);
#pragma unroll 4
        for (int yy = wlo; yy <= whi; ++yy) {
            const uint2 u = *(const uint2*)(AB + pb + (long long)yy * W_ + x0);
            const float2 a0 = __half22float2(*(const __half2*)&u.x);
            const float2 a1 = __half22float2(*(const __half2*)&u.y);
            s[0][0] += a0.x; s[1][0] += a0.y;
            s[0][1] += a1.x; s[1][1] += a1.y;
        }
    }

    for (int y = y0; y < y0 + SH; y += 2) {
        float ps[4][2], tot[4], wsc[4];

#pragma unroll
        for (int r = 0; r < 2; ++r) {
            const int yr = y + r;
#pragma unroll
            for (int f = 0; f < 2; ++f) {
                ps[r * 2 + f][0] = s[f][0];
                ps[r * 2 + f][1] = s[f][0] + s[f][1];
            }
            const int ya = yr + RAD + 1, yb = yr - RAD;
            if (ya < H_) {
                const uint2 u = *(const uint2*)(AB + pb + (long long)ya * W_ + x0);
                const float2 a0 = __half22float2(*(const __half2*)&u.x);
                const float2 a1 = __half22float2(*(const __half2*)&u.y);
                s[0][0] += a0.x; s[1][0] += a0.y;
                s[0][1] += a1.x; s[1][1] += a1.y;
            }
            if (yb >= 0) {
                const uint2 u = *(const uint2*)(AB + pb + (long long)yb * W_ + x0);
                const float2 a0 = __half22float2(*(const __half2*)&u.x);
                const float2 a1 = __half22float2(*(const __half2*)&u.y);
                s[0][0] -= a0.x; s[1][0] -= a0.y;
                s[0][1] -= a1.x; s[1][1] -= a1.y;
            }
        }

#pragma unroll
        for (int ch = 0; ch < 4; ++ch) {
            tot[ch] = ps[ch][1];
            wsc[ch] = wscan_dpp(tot[ch]);
        }
        if (lane == 63)
            WT[wid][0] = make_float4(wsc[0], wsc[1], wsc[2], wsc[3]);
        __syncthreads();   // b1

        float wo[4] = {0, 0, 0, 0};
        for (int w = 0; w < wid; ++w) {
            const float4 a = WT[w][0];
            wo[0] += a.x; wo[1] += a.y; wo[2] += a.z; wo[3] += a.w;
        }

        float pv1[4], pv2[4];
#pragma unroll
        for (int ch = 0; ch < 4; ++ch) {
            const float ex = wo[ch] + wsc[ch] - tot[ch];
            pv1[ch] = ex + ps[ch][0];
            pv2[ch] = ex + ps[ch][1];
        }
        {
            const int i1 = (x0 + 1) * 3, i2 = (x0 + 2) * 3;
            P2[i1 + 0] = make_float2(pv1[0], pv1[1]);
            P2[i1 + 1] = make_float2(pv1[2], pv1[3]);
            P2[i2 + 0] = make_float2(pv2[0], pv2[1]);
            P2[i2 + 1] = make_float2(pv2[2], pv2[3]);
        }
        __syncthreads();   // b2

#pragma unroll
        for (int r = 0; r < 2; ++r) {
            const int yr = y + r;
            const float icy = 1.0f / (float)(min(yr + RAD, H_ - 1) - max(yr - RAD, 0) + 1);
            const long long og = ib + (long long)yr * W_ + x0;
            const unsigned long long ru = nt_load_u64(Rimg + og);
            float rv[2];
            *(unsigned*)&rv[0] = (unsigned)(ru & 0xffffffffu);
            *(unsigned*)&rv[1] = (unsigned)(ru >> 32);
            float ov[2];
#pragma unroll
            for (int j = 0; j < 2; ++j) {
                const int x = x0 + j;
                const int hi = min(x + RAD + 1, W_) * 3;
                const int lo = max(x - RAD, 0) * 3;
                const float2 h2 = P2[hi + r];
                const float2 l2 = P2[lo + r];
                const float SA = h2.x - l2.x;
                const float SB = h2.y - l2.y;
                const float invN = icx[j] * icy;
                ov[j] = (SA * invN) * rv[j] + SB * invN;
            }
            unsigned long long uo =
                (unsigned long long)(*(const unsigned*)&ov[0]) |
                ((unsigned long long)(*(const unsigned*)&ov[1]) << 32);
            nt_store_u64(out + og, uo);
        }
        // no b3 (see gf_ab)
    }
}

// ---------------------------------------------------------------------------
extern "C" void kernel_launch(void* const* d_in, const int* in_sizes, int n_in,
                              void* d_out, int out_size, void* d_ws, size_t ws_size,
                              hipStream_t stream)
{
    const float* I = (const float*)d_in[0];   // image to filter
    const float* R = (const float*)d_in[1];   // guidance image
    float* out = (float*)d_out;

    const long long plane = (long long)H_ * W_;
    const int P_ = (int)(in_sizes[0] / plane);              // 24 planes
    const size_t ab_pb = (size_t)plane * sizeof(__half2);   // 4 MB/plane

    int CH = (int)(ws_size / ab_pb);
    if (CH > P_) CH = P_;
    if (CH < 1) CH = 1;

    __half2* AB = (__half2*)d_ws;

    for (int p0 = 0; p0 < P_; p0 += CH) {
        const int pc = (P_ - p0 < CH) ? (P_ - p0) : CH;
        const long long in_off = (long long)p0 * plane;
        const int nb = NSEG * pc;   // 32*pc

        hipLaunchKernelGGL(gf_ab, dim3(nb), dim3(NT), 0, stream,
                           I, R, in_off, nb, AB);
        hipLaunchKernelGGL(gf_cd, dim3(nb), dim3(NT), 0, stream,
                           AB, R, in_off, nb, out);
    }
}